// Round 6
// baseline (125.395 us; speedup 1.0000x reference)
//
#include <hip/hip_runtime.h>
#include <math.h>

// EfficientAttention, fp16-MFMA, register-dataflow version (no in-loop LDS).
//   ctx_h = softmax_N(k_h) @ v_h^T folded with Wr into M[n][oc][p] (p=h*16+kc):
//   out = M @ softmax_dk(q) + br.
// Key identity: mfma_f32_16x16x16f16's A/B fragment layouts equal the D
// layout of our projection MFMAs, so EK/EV (and qhat) feed the next MFMA
// directly from registers. bk drops out (softmax over N is shift-invariant
// per channel); bv folds into k_m exactly in fp32.

#define NTOK 262144
typedef float4 f4;
typedef _Float16 f16;
typedef __attribute__((ext_vector_type(8))) _Float16 f16x8;
typedef __attribute__((ext_vector_type(4))) _Float16 f16x4;
typedef __attribute__((ext_vector_type(4))) float f32x4;

// ---- workspace float offsets ----
#define WS_S  0      // 2048 : S[n][h][kc][vc] f32 (raw, no bv)
#define WS_Z  2048   // 128  : Z[n][h*16+kc]   f32
#define WS_MH 2176   // 4096 floats = 8192 f16 : M[n][c][p] f16

__device__ __forceinline__ f16x8 cvt8h2(f4 a, f4 b) {
    f16x8 r;
    r[0] = (f16)a.x; r[1] = (f16)a.y; r[2] = (f16)a.z; r[3] = (f16)a.w;
    r[4] = (f16)b.x; r[5] = (f16)b.y; r[6] = (f16)b.z; r[7] = (f16)b.w;
    return r;
}

__global__ __launch_bounds__(256) void k_init(float* __restrict__ ws) {
    int i = blockIdx.x * 256 + threadIdx.x;
    if (i < 2176) ws[i] = 0.0f;   // zero S and Z
}

// ---------------- Pass 1: k,v projection + ctx accumulation ----------------
// Wave w owns tokens [w*128, w*128+128), all 4 heads, 8 subtiles of 16.
// Proj: A = x rows (token=lr, j=8ql+m+32jc), B = Wk/Wv rows (c=16h+lr) ->
// D[t][c]: lane holds c=lr, t=4ql+r.  Acc: S_h += EK_h^T x EV_h via
// mfma_16x16x16f16 with ekf/evf = f16 of the D registers directly (A needs
// row kc=lr,k=t=4ql+m; B needs col vc=lr,k=t=4ql+m -- both == D layout).
__global__ __launch_bounds__(256, 4) void k_ctx(const float* __restrict__ x,
                                                const float* __restrict__ Wk,
                                                const float* __restrict__ Wv,
                                                float* __restrict__ ws) {
    __shared__ float sr[4096];   // epilogue: [w][h][kc][vc]
    __shared__ float zr[256];    // epilogue: [w][h][kc]

    const int tid  = threadIdx.x;
    const int w    = tid >> 6;
    const int lane = tid & 63;
    const int lr   = lane & 15;
    const int ql   = lane >> 4;

    const int nb = blockIdx.x >> 9;
    const int bi = blockIdx.x & 511;
    const long base = (long)nb * NTOK + (long)bi * 512 + (long)w * 128;

    // B-frags for all heads (f16, register-resident): lane c=16h+lr, k=32jc+8ql+m
    f16x8 wkf[4][2], wvf[4][2];
    #pragma unroll
    for (int h = 0; h < 4; ++h) {
        const float* kr = &Wk[(16 * h + lr) * 64 + 8 * ql];
        const float* vr = &Wv[(16 * h + lr) * 64 + 8 * ql];
        #pragma unroll
        for (int jc = 0; jc < 2; ++jc) {
            wkf[h][jc] = cvt8h2(*(const f4*)&kr[32 * jc], *(const f4*)&kr[32 * jc + 4]);
            wvf[h][jc] = cvt8h2(*(const f4*)&vr[32 * jc], *(const f4*)&vr[32 * jc + 4]);
        }
    }

    const f32x4 zero4 = {0.f, 0.f, 0.f, 0.f};
    f32x4 S[4] = {zero4, zero4, zero4, zero4};
    float z[4] = {0.f, 0.f, 0.f, 0.f};

    // prefetch subtile 0
    f4 L0, L1, L2, L3;
    {
        const float* xp = x + (((size_t)(base + lr)) << 6) + 8 * ql;
        L0 = *(const f4*)xp;        L1 = *(const f4*)(xp + 4);
        L2 = *(const f4*)(xp + 32); L3 = *(const f4*)(xp + 36);
    }

    for (int s = 0; s < 8; ++s) {
        f16x8 a0 = cvt8h2(L0, L1), a1 = cvt8h2(L2, L3);
        if (s < 7) {                      // prefetch next subtile
            const float* xp = x + (((size_t)(base + (s + 1) * 16 + lr)) << 6) + 8 * ql;
            L0 = *(const f4*)xp;        L1 = *(const f4*)(xp + 4);
            L2 = *(const f4*)(xp + 32); L3 = *(const f4*)(xp + 36);
        }
        #pragma unroll
        for (int h = 0; h < 4; ++h) {
            f32x4 ak = zero4, av = zero4;
            ak = __builtin_amdgcn_mfma_f32_16x16x32_f16(a0, wkf[h][0], ak, 0, 0, 0);
            ak = __builtin_amdgcn_mfma_f32_16x16x32_f16(a1, wkf[h][1], ak, 0, 0, 0);
            av = __builtin_amdgcn_mfma_f32_16x16x32_f16(a0, wvf[h][0], av, 0, 0, 0);
            av = __builtin_amdgcn_mfma_f32_16x16x32_f16(a1, wvf[h][1], av, 0, 0, 0);
            // no bk: softmax over spatial axis is invariant to per-channel shift
            const float e0 = __expf(ak[0]), e1 = __expf(ak[1]);
            const float e2 = __expf(ak[2]), e3 = __expf(ak[3]);
            z[h] += (e0 + e1) + (e2 + e3);
            f16x4 ekf = {(f16)e0, (f16)e1, (f16)e2, (f16)e3};
            f16x4 evf = {(f16)av[0], (f16)av[1], (f16)av[2], (f16)av[3]};
            S[h] = __builtin_amdgcn_mfma_f32_16x16x16f16(ekf, evf, S[h], 0, 0, 0);
        }
    }

    // z: quartile lanes (lr, lr+16, lr+32, lr+48) hold same kc=lr
    #pragma unroll
    for (int h = 0; h < 4; ++h) {
        z[h] += __shfl_xor(z[h], 16);
        z[h] += __shfl_xor(z[h], 32);
    }

    // block-level reduction of S,z in LDS, then atomics.
    // S D-layout: col vc=lr, row kc=4ql+r.
    #pragma unroll
    for (int h = 0; h < 4; ++h) {
        #pragma unroll
        for (int r = 0; r < 4; ++r)
            sr[((w * 4 + h) * 16 + 4 * ql + r) * 16 + lr] = S[h][r];
        if (lane < 16) zr[(w * 4 + h) * 16 + lane] = z[h];
    }
    __syncthreads();
    #pragma unroll
    for (int i = 0; i < 4; ++i) {
        const int idx = i * 256 + tid;     // h=i, kc=tid>>4, vc=tid&15
        const float acc = sr[idx] + sr[1024 + idx] + sr[2048 + idx] + sr[3072 + idx];
        atomicAdd(&ws[WS_S + nb * 1024 + idx], acc);
    }
    if (tid < 64) {
        const float acc = zr[tid] + zr[64 + tid] + zr[128 + tid] + zr[192 + tid];
        atomicAdd(&ws[WS_Z + nb * 64 + tid], acc);
    }
}

// ---------- M = Wr @ (S/Z + bv) fold : M[n][c][p] in fp16 ----------
// ctx[kc][vc] = S_raw[kc][vc]/z[kc] + bv[vc]  (bv folded exactly in fp32)
__global__ __launch_bounds__(256) void k_m(const float* __restrict__ Wr,
                                           const float* __restrict__ bv,
                                           float* __restrict__ ws) {
    const int n = blockIdx.x;
    f16* MH = (f16*)(ws + WS_MH);
    for (int i = threadIdx.x; i < 4096; i += 256) {
        const int c = i >> 6, p = i & 63;
        const int h = p >> 4, kc = p & 15;
        const float rz = 1.0f / ws[WS_Z + n * 64 + p];
        const float* Srow = ws + WS_S + n * 1024 + h * 256 + kc * 16;
        const float* Wrow = Wr + c * 64 + h * 16;
        const float* bvr  = bv + h * 16;
        float acc = 0.f, accb = 0.f;
        #pragma unroll
        for (int vc = 0; vc < 16; ++vc) {
            acc  += Wrow[vc] * Srow[vc];
            accb += Wrow[vc] * bvr[vc];
        }
        MH[n * 4096 + c * 64 + p] = (f16)(acc * rz + accb);
    }
}

// ---------------- Pass 2: q proj + softmax + M apply (fp16) ----------------
// Wave w owns tokens [w*64, w*64+64); all heads/oc-tiles; 4 subtiles of 16.
// Phase A: D_q[c][t] = Wq(A) x X^T(B), softmax over c (regs + shfl 16/32).
// Phase B: out[oc][t] = sum_pc mfma_16x16x16f16(M-frag[oct][pc], qf[pc], .)
// where qf[h] (the phase-A D registers, f16) IS the required B-frag.
// No LDS, no barriers.
__global__ __launch_bounds__(256, 4) void k_out(const float* __restrict__ x,
                                                const float* __restrict__ Wq,
                                                const float* __restrict__ bq,
                                                const float* __restrict__ br,
                                                float* __restrict__ out,
                                                const float* __restrict__ ws) {
    const int tid  = threadIdx.x;
    const int w    = tid >> 6;
    const int lane = tid & 63;
    const int lr   = lane & 15;
    const int ql   = lane >> 4;

    const int nb = blockIdx.x >> 10;
    const int bi = blockIdx.x & 1023;
    const long base = (long)nb * NTOK + (long)bi * 256 + (long)w * 64;

    // Wq A-frags for all heads: lane row c(within head)=lr, k=32jc+8ql+m
    f16x8 wqf[4][2];
    f16x4 bqh[4];
    #pragma unroll
    for (int h = 0; h < 4; ++h) {
        const float* qr = &Wq[(16 * h + lr) * 64 + 8 * ql];
        #pragma unroll
        for (int jc = 0; jc < 2; ++jc)
            wqf[h][jc] = cvt8h2(*(const f4*)&qr[32 * jc], *(const f4*)&qr[32 * jc + 4]);
        const f4 b = *(const f4*)&bq[16 * h + 4 * ql];
        bqh[h][0] = (f16)b.x; bqh[h][1] = (f16)b.y;
        bqh[h][2] = (f16)b.z; bqh[h][3] = (f16)b.w;
    }
    // M A-frags for 16x16x16: [oct][pc], lane row oc=16oct+lr, k=p=16pc+4ql+m
    f16x4 mfa[4][4];
    f16x4 brh[4];
    const f16* MH = (const f16*)(ws + WS_MH) + (size_t)nb * 4096;
    #pragma unroll
    for (int oct = 0; oct < 4; ++oct) {
        #pragma unroll
        for (int pc = 0; pc < 4; ++pc)
            mfa[oct][pc] = *(const f16x4*)&MH[(16 * oct + lr) * 64 + 16 * pc + 4 * ql];
        const f4 b = *(const f4*)&br[16 * oct + 4 * ql];
        brh[oct][0] = (f16)b.x; brh[oct][1] = (f16)b.y;
        brh[oct][2] = (f16)b.z; brh[oct][3] = (f16)b.w;
    }

    const f32x4 zero4 = {0.f, 0.f, 0.f, 0.f};

    // prefetch subtile 0
    f4 L0, L1, L2, L3;
    {
        const float* xp = x + (((size_t)(base + lr)) << 6) + 8 * ql;
        L0 = *(const f4*)xp;        L1 = *(const f4*)(xp + 4);
        L2 = *(const f4*)(xp + 32); L3 = *(const f4*)(xp + 36);
    }

    for (int s = 0; s < 4; ++s) {
        f16x8 b0 = cvt8h2(L0, L1), b1 = cvt8h2(L2, L3);
        if (s < 3) {
            const float* xp = x + (((size_t)(base + (s + 1) * 16 + lr)) << 6) + 8 * ql;
            L0 = *(const f4*)xp;        L1 = *(const f4*)(xp + 4);
            L2 = *(const f4*)(xp + 32); L3 = *(const f4*)(xp + 36);
        }
        // phase A: q projection + per-head softmax over c; qf[h] = B-frag
        f16x4 qf[4];
        #pragma unroll
        for (int h = 0; h < 4; ++h) {
            f32x4 aq = zero4;
            aq = __builtin_amdgcn_mfma_f32_16x16x32_f16(wqf[h][0], b0, aq, 0, 0, 0);
            aq = __builtin_amdgcn_mfma_f32_16x16x32_f16(wqf[h][1], b1, aq, 0, 0, 0);
            float q0 = aq[0] + (float)bqh[h][0], q1 = aq[1] + (float)bqh[h][1];
            float q2 = aq[2] + (float)bqh[h][2], q3 = aq[3] + (float)bqh[h][3];
            float mx = fmaxf(fmaxf(q0, q1), fmaxf(q2, q3));
            mx = fmaxf(mx, __shfl_xor(mx, 16));
            mx = fmaxf(mx, __shfl_xor(mx, 32));
            float e0 = __expf(q0 - mx), e1 = __expf(q1 - mx);
            float e2 = __expf(q2 - mx), e3 = __expf(q3 - mx);
            float sm = (e0 + e1) + (e2 + e3);
            sm += __shfl_xor(sm, 16);
            sm += __shfl_xor(sm, 32);
            const float rs = 1.0f / sm;
            qf[h][0] = (f16)(e0 * rs); qf[h][1] = (f16)(e1 * rs);
            qf[h][2] = (f16)(e2 * rs); qf[h][3] = (f16)(e3 * rs);
        }
        // phase B: out = M x qhat + br, all in registers
        const size_t obase = ((size_t)(base + s * 16 + lr)) << 6;
        #pragma unroll
        for (int oct = 0; oct < 4; ++oct) {
            f32x4 o = zero4;
            #pragma unroll
            for (int pc = 0; pc < 4; ++pc)
                o = __builtin_amdgcn_mfma_f32_16x16x16f16(mfa[oct][pc], qf[pc], o, 0, 0, 0);
            const f4 res = {o[0] + (float)brh[oct][0], o[1] + (float)brh[oct][1],
                            o[2] + (float)brh[oct][2], o[3] + (float)brh[oct][3]};
            *(f4*)&out[obase + 16 * oct + 4 * ql] = res;
        }
    }
}

extern "C" void kernel_launch(void* const* d_in, const int* in_sizes, int n_in,
                              void* d_out, int out_size, void* d_ws, size_t ws_size,
                              hipStream_t stream) {
    const float* x  = (const float*)d_in[0];
    const float* Wk = (const float*)d_in[1];
    const float* Wq = (const float*)d_in[3];
    const float* bq = (const float*)d_in[4];
    const float* Wv = (const float*)d_in[5];
    const float* bv = (const float*)d_in[6];
    const float* Wr = (const float*)d_in[7];
    const float* br = (const float*)d_in[8];
    float* out = (float*)d_out;
    float* ws  = (float*)d_ws;

    hipLaunchKernelGGL(k_init, dim3(9),    dim3(256), 0, stream, ws);
    hipLaunchKernelGGL(k_ctx,  dim3(1024), dim3(256), 0, stream, x, Wk, Wv, ws);
    hipLaunchKernelGGL(k_m,    dim3(2),    dim3(256), 0, stream, Wr, bv, ws);
    hipLaunchKernelGGL(k_out,  dim3(2048), dim3(256), 0, stream, x, Wq, bq, br, out, ws);
}